// Round 3
// baseline (191.549 us; speedup 1.0000x reference)
//
#include <hip/hip_runtime.h>
#include <hip/hip_bf16.h>

// Problem: B=512, D=128, H=512.
// out[a,b] = W2 . relu( x[a]@W1x + y[b]@W1y + b1 ) + b2
// relu(t) = (t+|t|)/2  =>  with U[a,h]=x[a]@W1x+b1, V[b,h]=y[b]@W1y:
//   out[a,b] = b2 + P[a] + Q[b] + 0.5*sum_h |U[a,h]+V[b,h]|*W2[h]
// Single fused kernel, 512 blocks x 256 thr (all co-resident: 35KB LDS/block
// -> 4 blocks/CU capacity, need only 2/CU), hand-rolled grid barrier.

#define B 512
#define D 128
#define H 512
#define CH 64      // h-slice per phase-2 block (S = H/CH = 8 planes)
#define LDP 68     // padded LDS row stride
#define NBLK 512
#define NTHR 256

union Smem {
    struct { float xs[4][D]; float red[4][4]; } p1;
    struct { float Us[CH][LDP]; float Vs[CH][LDP]; float w2s[CH]; } p2;
};

__device__ __forceinline__ void grid_barrier(int* cnt, int* gen) {
    __syncthreads();
    if (threadIdx.x == 0) {
        __threadfence();  // release: make this block's prior writes device-visible
        int g = __hip_atomic_load(gen, __ATOMIC_RELAXED, __HIP_MEMORY_SCOPE_AGENT);
        int old = __hip_atomic_fetch_add(cnt, 1, __ATOMIC_ACQ_REL, __HIP_MEMORY_SCOPE_AGENT);
        if (old == NBLK - 1) {
            __hip_atomic_store(cnt, 0, __ATOMIC_RELAXED, __HIP_MEMORY_SCOPE_AGENT);
            __hip_atomic_store(gen, g + 1, __ATOMIC_RELEASE, __HIP_MEMORY_SCOPE_AGENT);
        } else {
            while (__hip_atomic_load(gen, __ATOMIC_ACQUIRE, __HIP_MEMORY_SCOPE_AGENT) == g)
                __builtin_amdgcn_s_sleep(2);
        }
        __threadfence();  // acquire: invalidate stale cached lines
    }
    __syncthreads();
}

__global__ __launch_bounds__(NTHR) void fused_all(
        const float* __restrict__ x, const float* __restrict__ y,
        const float* __restrict__ W1, const float* __restrict__ b1,
        const float* __restrict__ W2, const float* __restrict__ b2,
        float* __restrict__ U, float* __restrict__ V,
        float* __restrict__ PQ, float* __restrict__ Pp,
        int* cnt, int* gen, float* __restrict__ out) {
    __shared__ Smem sm;
    const int bid = blockIdx.x;
    const int t = threadIdx.x;

    // ---------------- Phase 1: U,V + P/Q rank-1 terms ----------------
    {
        const int m  = bid & 1;
        const int z2 = (bid >> 1) & 1;
        const int a0 = (bid >> 2) * 4;
        const float* __restrict__ src = m ? y : x;
        float* __restrict__ dst       = m ? V : U;
        const float* __restrict__ Wm  = W1 + (size_t)m * D * H;

        for (int i = t; i < 4 * D; i += NTHR)
            sm.p1.xs[i >> 7][i & (D - 1)] = src[(size_t)(a0 + (i >> 7)) * D + (i & (D - 1))];
        __syncthreads();

        const int h = z2 * 256 + t;
        const float bias = m ? 0.0f : b1[h];
        float acc[4] = {bias, bias, bias, bias};
#pragma unroll 8
        for (int d = 0; d < D; ++d) {
            const float w = Wm[(size_t)d * H + h];
#pragma unroll
            for (int r = 0; r < 4; ++r) acc[r] = fmaf(sm.p1.xs[r][d], w, acc[r]);
        }
#pragma unroll
        for (int r = 0; r < 4; ++r) dst[(size_t)(a0 + r) * H + h] = acc[r];

        const float wp = 0.5f * W2[h];
        float v[4];
#pragma unroll
        for (int r = 0; r < 4; ++r) v[r] = acc[r] * wp;
#pragma unroll
        for (int r = 0; r < 4; ++r)
            for (int o = 32; o > 0; o >>= 1) v[r] += __shfl_down(v[r], o);
        const int wave = t >> 6;
        if ((t & 63) == 0)
#pragma unroll
            for (int r = 0; r < 4; ++r) sm.p1.red[wave][r] = v[r];
        __syncthreads();
        if (t < 4) {
            const float s = sm.p1.red[0][t] + sm.p1.red[1][t] +
                            sm.p1.red[2][t] + sm.p1.red[3][t];
            PQ[(size_t)(m * 2 + z2) * B + a0 + t] = s;
        }
    }

    grid_barrier(cnt, gen);

    // ---------------- Phase 2: Pp[z][a,b] = sum_{h in slice} |U+V|*W2 ------
    {
        const int z  = bid >> 6;
        const int a0 = ((bid >> 3) & 7) * 64;
        const int b0 = (bid & 7) * 64;
        const int h0 = z * CH;
        const int r = t >> 2, q = t & 3;

        const float* __restrict__ Urow = U + (size_t)(a0 + r) * H + h0;
        const float* __restrict__ Vrow = V + (size_t)(b0 + r) * H + h0;
#pragma unroll
        for (int p = 0; p < 4; ++p) {
            const int hh = 4 * q + 16 * p;
            const float4 u4 = *(const float4*)(Urow + hh);
            const float4 v4 = *(const float4*)(Vrow + hh);
            sm.p2.Us[hh + 0][r] = u4.x; sm.p2.Us[hh + 1][r] = u4.y;
            sm.p2.Us[hh + 2][r] = u4.z; sm.p2.Us[hh + 3][r] = u4.w;
            sm.p2.Vs[hh + 0][r] = v4.x; sm.p2.Vs[hh + 1][r] = v4.y;
            sm.p2.Vs[hh + 2][r] = v4.z; sm.p2.Vs[hh + 3][r] = v4.w;
        }
        if (t < CH) sm.p2.w2s[t] = W2[h0 + t];
        __syncthreads();

        const int ta = t & 15, tb = t >> 4;
        float acc[4][4] = {};
#pragma unroll 4
        for (int hh = 0; hh < CH; ++hh) {
            const float w = sm.p2.w2s[hh];
            const float4 ua = *(const float4*)&sm.p2.Us[hh][4 * ta];
            const float4 vb = *(const float4*)&sm.p2.Vs[hh][4 * tb];
            const float u[4] = {ua.x, ua.y, ua.z, ua.w};
            const float v[4] = {vb.x, vb.y, vb.z, vb.w};
#pragma unroll
            for (int i = 0; i < 4; ++i)
#pragma unroll
                for (int j = 0; j < 4; ++j)
                    acc[i][j] = fmaf(__builtin_fabsf(u[i] + v[j]), w, acc[i][j]);
        }

        float* __restrict__ outp = Pp + (size_t)z * (B * B);
#pragma unroll
        for (int i = 0; i < 4; ++i) {
            float4 o;
            o.x = acc[i][0]; o.y = acc[i][1]; o.z = acc[i][2]; o.w = acc[i][3];
            *(float4*)(outp + (size_t)(a0 + 4 * ta + i) * B + b0 + 4 * tb) = o;
        }
    }

    grid_barrier(cnt, gen);

    // ---------------- Phase 3: out = b2 + P[a] + Q[b] + 0.5*sum_z ----------
    if (t < 128) {
        const int i = bid * 512 + t * 4;   // block bid covers output row a=bid
        const int b = t * 4;
        float4 s = {0.f, 0.f, 0.f, 0.f};
#pragma unroll
        for (int z = 0; z < H / CH; ++z) {
            const float4 p = *(const float4*)(Pp + (size_t)z * (B * B) + i);
            s.x += p.x; s.y += p.y; s.z += p.z; s.w += p.w;
        }
        const float pa = PQ[bid] + PQ[B + bid] + b2[0];
        const float4 q0 = *(const float4*)(PQ + 2 * B + b);
        const float4 q1 = *(const float4*)(PQ + 3 * B + b);
        float4 o;
        o.x = pa + q0.x + q1.x + 0.5f * s.x;
        o.y = pa + q0.y + q1.y + 0.5f * s.y;
        o.z = pa + q0.z + q1.z + 0.5f * s.z;
        o.w = pa + q0.w + q1.w + 0.5f * s.w;
        *(float4*)(out + i) = o;
    }
}

extern "C" void kernel_launch(void* const* d_in, const int* in_sizes, int n_in,
                              void* d_out, int out_size, void* d_ws, size_t ws_size,
                              hipStream_t stream) {
    const float* x  = (const float*)d_in[0];
    const float* y  = (const float*)d_in[1];
    const float* W1 = (const float*)d_in[2];
    const float* b1 = (const float*)d_in[3];
    const float* W2 = (const float*)d_in[4];
    const float* b2 = (const float*)d_in[5];
    float* out = (float*)d_out;

    int* cnt = (int*)d_ws;                       // [0]
    int* gen = (int*)d_ws + 1;                   // [1]
    float* U  = (float*)d_ws + 16;               // 64-B offset past barrier line
    float* V  = U + (size_t)B * H;
    float* PQ = V + (size_t)B * H;
    float* Pp = PQ + 4 * B;                      // 8 planes of B*B

    hipMemsetAsync(d_ws, 0, 64, stream);         // zero barrier state each call
    fused_all<<<NBLK, NTHR, 0, stream>>>(x, y, W1, b1, W2, b2,
                                         U, V, PQ, Pp, cnt, gen, out);
}

// Round 4
// 43.175 us; speedup vs baseline: 4.4366x; 4.4366x over previous
//
#include <hip/hip_runtime.h>
#include <hip/hip_bf16.h>

// Problem: B=512, D=128, H=512.
// out[a,b] = W2 . relu( x[a]@W1x + y[b]@W1y + b1 ) + b2
// relu(t) = (t+|t|)/2  =>  with U[a,h]=x[a]@W1x+b1, V[b,h]=y[b]@W1y:
//   out[a,b] = b2 + P[a] + Q[b] + 0.5*sum_h |U[a,h]+V[b,h]|*W2[h]
// Two kernels:
//   K1: U,V GEMM + P/Q rank-1 terms (+ zero the split-K tile counters).
//   K2: per (a-tile, b-tile, h-slice) partial planes; LAST block per tile
//       (fence-free: sc1 write-through stores + vmcnt drain + relaxed
//       fetch_add) re-reads all 8 planes in fixed order + epilogue -> out.

#define B 512
#define D 128
#define H 512
#define CH 64      // h-slice per K2 block (8 planes)
#define LDP 68     // padded LDS row stride

// ---------------- K1: U = x@W1x + b1, V = y@W1y, P/Q, counter zero --------
// grid (B/4, 2, 2), block 256.
__global__ __launch_bounds__(256) void k1_uv(
        const float* __restrict__ x, const float* __restrict__ y,
        const float* __restrict__ W1, const float* __restrict__ b1,
        const float* __restrict__ W2,
        float* __restrict__ U, float* __restrict__ V, float* __restrict__ PQ,
        int* __restrict__ cnt) {
    const int m  = blockIdx.y;
    const int z  = blockIdx.z;
    const int a0 = blockIdx.x * 4;
    const int t = threadIdx.x;

    if (blockIdx.x == 0 && m == 0 && z == 0 && t < 64)
        __hip_atomic_store(&cnt[t], 0, __ATOMIC_RELAXED, __HIP_MEMORY_SCOPE_AGENT);

    const float* __restrict__ src = (m == 0) ? x : y;
    float* __restrict__ dst       = (m == 0) ? U : V;
    const float* __restrict__ Wm  = W1 + (size_t)m * D * H;

    __shared__ float xs[4][D];
    __shared__ float red[4][4];
    for (int i = t; i < 4 * D; i += 256)
        xs[i >> 7][i & (D - 1)] = src[(size_t)(a0 + (i >> 7)) * D + (i & (D - 1))];
    __syncthreads();

    const int h = z * 256 + t;
    const float bias = (m == 0) ? b1[h] : 0.0f;
    float acc[4] = {bias, bias, bias, bias};
#pragma unroll 8
    for (int d = 0; d < D; ++d) {
        const float w = Wm[(size_t)d * H + h];
#pragma unroll
        for (int r = 0; r < 4; ++r) acc[r] = fmaf(xs[r][d], w, acc[r]);
    }
#pragma unroll
    for (int r = 0; r < 4; ++r) dst[(size_t)(a0 + r) * H + h] = acc[r];

    const float wp = 0.5f * W2[h];
    float v[4];
#pragma unroll
    for (int r = 0; r < 4; ++r) v[r] = acc[r] * wp;
#pragma unroll
    for (int r = 0; r < 4; ++r)
        for (int o = 32; o > 0; o >>= 1) v[r] += __shfl_down(v[r], o);
    const int wave = t >> 6;
    if ((t & 63) == 0)
#pragma unroll
        for (int r = 0; r < 4; ++r) red[wave][r] = v[r];
    __syncthreads();
    if (t < 4) {
        const float s = red[0][t] + red[1][t] + red[2][t] + red[3][t];
        PQ[(size_t)(m * 2 + z) * B + a0 + t] = s;
    }
}

// ---------------- K2: split-K planes + last-block reduction ----------------
// grid (8, 8, 8): x=a-tile, y=b-tile, z=h-slice. block 256, 4x4 per thread.
__global__ __launch_bounds__(256) void k2_fused(
        const float* __restrict__ U, const float* __restrict__ V,
        const float* __restrict__ W2, const float* __restrict__ PQ,
        const float* __restrict__ b2, float* __restrict__ Pp,
        int* __restrict__ cnt, float* __restrict__ out) {
    __shared__ float Us[CH][LDP];
    __shared__ float Vs[CH][LDP];
    __shared__ float w2s[CH];
    __shared__ int lastFlag;

    const int a0 = blockIdx.x * 64;
    const int b0 = blockIdx.y * 64;
    const int zp = blockIdx.z;
    const int h0 = zp * CH;
    const int t = threadIdx.x;
    const int ta = t & 15;     // a-quad
    const int tb = t >> 4;     // b-quad
    const int r = t >> 2;      // staging row 0..63
    const int q = t & 3;       // staging h-quad

    const float* __restrict__ Urow = U + (size_t)(a0 + r) * H + h0;
    const float* __restrict__ Vrow = V + (size_t)(b0 + r) * H + h0;
#pragma unroll
    for (int p = 0; p < 4; ++p) {
        const int hh = 4 * q + 16 * p;
        const float4 u4 = *(const float4*)(Urow + hh);
        const float4 v4 = *(const float4*)(Vrow + hh);
        Us[hh + 0][r] = u4.x; Us[hh + 1][r] = u4.y;
        Us[hh + 2][r] = u4.z; Us[hh + 3][r] = u4.w;
        Vs[hh + 0][r] = v4.x; Vs[hh + 1][r] = v4.y;
        Vs[hh + 2][r] = v4.z; Vs[hh + 3][r] = v4.w;
    }
    if (t < CH) w2s[t] = W2[h0 + t];
    __syncthreads();

    float acc[4][4] = {};
#pragma unroll 4
    for (int hh = 0; hh < CH; ++hh) {
        const float w = w2s[hh];
        const float4 ua = *(const float4*)&Us[hh][4 * ta];
        const float4 vb = *(const float4*)&Vs[hh][4 * tb];
        const float u[4] = {ua.x, ua.y, ua.z, ua.w};
        const float v[4] = {vb.x, vb.y, vb.z, vb.w};
#pragma unroll
        for (int i = 0; i < 4; ++i)
#pragma unroll
            for (int j = 0; j < 4; ++j)
                acc[i][j] = fmaf(__builtin_fabsf(u[i] + v[j]), w, acc[i][j]);
    }

    // Publish partial plane via write-through (agent-scope relaxed) stores.
    float* __restrict__ outp = Pp + (size_t)zp * (B * B);
#pragma unroll
    for (int i = 0; i < 4; ++i)
#pragma unroll
        for (int j = 0; j < 4; ++j)
            __hip_atomic_store(&outp[(size_t)(a0 + 4 * ta + i) * B + b0 + 4 * tb + j],
                               acc[i][j], __ATOMIC_RELAXED, __HIP_MEMORY_SCOPE_AGENT);

    // Hand-rolled release without cache maintenance: drain this wave's
    // write-through stores, sync block, then a relaxed fabric fetch_add.
    asm volatile("s_waitcnt vmcnt(0)" ::: "memory");
    __syncthreads();
    if (t == 0) {
        const int old = __hip_atomic_fetch_add(&cnt[blockIdx.y * 8 + blockIdx.x], 1,
                                               __ATOMIC_RELAXED, __HIP_MEMORY_SCOPE_AGENT);
        lastFlag = (old == 7);
    }
    __syncthreads();

    if (lastFlag) {
        // Deterministic: re-read ALL 8 planes (incl. our own) in fixed order.
        const int a = a0 + 4 * ta;
        const int b = b0 + 4 * tb;
        const float bb = b2[0];
#pragma unroll
        for (int i = 0; i < 4; ++i) {
            const float pa = PQ[a + i] + PQ[B + a + i] + bb;
#pragma unroll
            for (int j = 0; j < 4; ++j) {
                float s = 0.0f;
#pragma unroll
                for (int zz = 0; zz < 8; ++zz)
                    s += __hip_atomic_load(&Pp[(size_t)zz * (B * B) + (size_t)(a + i) * B + b + j],
                                           __ATOMIC_RELAXED, __HIP_MEMORY_SCOPE_AGENT);
                const float qb = PQ[2 * B + b + j] + PQ[3 * B + b + j];
                out[(size_t)(a + i) * B + b + j] = pa + qb + 0.5f * s;
            }
        }
    }
}

extern "C" void kernel_launch(void* const* d_in, const int* in_sizes, int n_in,
                              void* d_out, int out_size, void* d_ws, size_t ws_size,
                              hipStream_t stream) {
    const float* x  = (const float*)d_in[0];
    const float* y  = (const float*)d_in[1];
    const float* W1 = (const float*)d_in[2];
    const float* b1 = (const float*)d_in[3];
    const float* W2 = (const float*)d_in[4];
    const float* b2 = (const float*)d_in[5];
    float* out = (float*)d_out;

    int* cnt  = (int*)d_ws;                       // 64 counters (256 B)
    float* U  = (float*)((char*)d_ws + 1024);     // B*H floats = 1 MB
    float* V  = U + (size_t)B * H;                // 1 MB
    float* PQ = V + (size_t)B * H;                // 4*B floats
    float* Pp = PQ + 4 * B;                       // 8 planes of B*B = 8 MB

    k1_uv<<<dim3(B / 4, 2, 2), 256, 0, stream>>>(x, y, W1, b1, W2, U, V, PQ, cnt);
    k2_fused<<<dim3(8, 8, 8), 256, 0, stream>>>(U, V, W2, PQ, b2, Pp, cnt, out);
}

// Round 5
// 32.387 us; speedup vs baseline: 5.9143x; 1.3331x over previous
//
#include <hip/hip_runtime.h>
#include <hip/hip_bf16.h>

// Problem: B=512, D=128, H=512.
// out[a,b] = W2 . relu( x[a]@W1x + y[b]@W1y + b1 ) + b2
// relu(t) = (t+|t|)/2  =>  with U[a,h]=x[a]@W1x+b1, V[b,h]=y[b]@W1y:
//   out[a,b] = b2 + P[a] + Q[b] + 0.5*sum_h |U[a,h]+V[b,h]|*W2[h]
// Two kernels, forward dataflow only (no cross-block sync — R3/R4 showed
// grid barriers / split-K tails cost 10-130 us on this chip):
//   K1: U,V GEMM + P/Q rank-1 terms.
//   K2: 32x32 output tile per block, FULL H loop in LDS chunks, epilogue
//       (P[a]+Q[b]+b2) fused -> writes out directly. 256 blocks = 1/CU.

#define B 512
#define D 128
#define H 512
#define CH 64      // h-chunk staged in LDS per K2 iteration
#define LDP 34     // padded LDS row stride for 32-wide tiles (float2 aligned)

// ---------------- K1: U = x@W1x + b1, V = y@W1y, P/Q ----------------------
// grid (B/4, 2, 2), block 256. y: m (0->U,1->V); z: h-half. 4 rows x 1 h/thr.
__global__ __launch_bounds__(256) void k1_uv(
        const float* __restrict__ x, const float* __restrict__ y,
        const float* __restrict__ W1, const float* __restrict__ b1,
        const float* __restrict__ W2,
        float* __restrict__ U, float* __restrict__ V, float* __restrict__ PQ) {
    const int m  = blockIdx.y;
    const int z  = blockIdx.z;
    const int a0 = blockIdx.x * 4;
    const int t  = threadIdx.x;

    const float* __restrict__ src = (m == 0) ? x : y;
    float* __restrict__ dst       = (m == 0) ? U : V;
    const float* __restrict__ Wm  = W1 + (size_t)m * D * H;

    __shared__ float xs[4][D];
    __shared__ float red[4][4];
    for (int i = t; i < 4 * D; i += 256)
        xs[i >> 7][i & (D - 1)] = src[(size_t)(a0 + (i >> 7)) * D + (i & (D - 1))];
    __syncthreads();

    const int h = z * 256 + t;
    const float bias = (m == 0) ? b1[h] : 0.0f;
    float acc[4] = {bias, bias, bias, bias};
#pragma unroll 8
    for (int d = 0; d < D; ++d) {
        const float w = Wm[(size_t)d * H + h];
#pragma unroll
        for (int r = 0; r < 4; ++r) acc[r] = fmaf(xs[r][d], w, acc[r]);
    }
#pragma unroll
    for (int r = 0; r < 4; ++r) dst[(size_t)(a0 + r) * H + h] = acc[r];

    const float wp = 0.5f * W2[h];
    float v[4];
#pragma unroll
    for (int r = 0; r < 4; ++r) v[r] = acc[r] * wp;
#pragma unroll
    for (int r = 0; r < 4; ++r)
        for (int o = 32; o > 0; o >>= 1) v[r] += __shfl_down(v[r], o);
    const int wave = t >> 6;
    if ((t & 63) == 0)
#pragma unroll
        for (int r = 0; r < 4; ++r) red[wave][r] = v[r];
    __syncthreads();
    if (t < 4) {
        const float s = red[0][t] + red[1][t] + red[2][t] + red[3][t];
        PQ[(size_t)(m * 2 + z) * B + a0 + t] = s;
    }
}

// ---------------- K2: out tile 32x32, full-H loop, fused epilogue ----------
// grid (16, 16), block 256; thread computes 2x2 outputs.
__global__ __launch_bounds__(256) void k2_pair(
        const float* __restrict__ U, const float* __restrict__ V,
        const float* __restrict__ W2, const float* __restrict__ PQ,
        const float* __restrict__ b2, float* __restrict__ out) {
    __shared__ float Us[CH][LDP];
    __shared__ float Vs[CH][LDP];
    __shared__ float w2s[CH];

    const int a0 = blockIdx.x * 32;
    const int b0 = blockIdx.y * 32;
    const int t  = threadIdx.x;
    const int ta = t & 15;     // a-pair index
    const int tb = t >> 4;     // b-pair index
    const int r  = t >> 3;     // staging row 0..31
    const int q  = t & 7;      // staging h-quad

    float acc[2][2] = {};

    for (int c = 0; c < H; c += CH) {
        const float* __restrict__ Urow = U + (size_t)(a0 + r) * H + c;
        const float* __restrict__ Vrow = V + (size_t)(b0 + r) * H + c;
#pragma unroll
        for (int p = 0; p < 2; ++p) {
            const int hh = 4 * q + 32 * p;
            const float4 u4 = *(const float4*)(Urow + hh);
            const float4 v4 = *(const float4*)(Vrow + hh);
            Us[hh + 0][r] = u4.x; Us[hh + 1][r] = u4.y;
            Us[hh + 2][r] = u4.z; Us[hh + 3][r] = u4.w;
            Vs[hh + 0][r] = v4.x; Vs[hh + 1][r] = v4.y;
            Vs[hh + 2][r] = v4.z; Vs[hh + 3][r] = v4.w;
        }
        if (t < CH) w2s[t] = W2[c + t];
        __syncthreads();

#pragma unroll 8
        for (int hh = 0; hh < CH; ++hh) {
            const float w = w2s[hh];
            const float2 ua = *(const float2*)&Us[hh][2 * ta];
            const float2 vb = *(const float2*)&Vs[hh][2 * tb];
            acc[0][0] = fmaf(__builtin_fabsf(ua.x + vb.x), w, acc[0][0]);
            acc[0][1] = fmaf(__builtin_fabsf(ua.x + vb.y), w, acc[0][1]);
            acc[1][0] = fmaf(__builtin_fabsf(ua.y + vb.x), w, acc[1][0]);
            acc[1][1] = fmaf(__builtin_fabsf(ua.y + vb.y), w, acc[1][1]);
        }
        __syncthreads();
    }

    const int a = a0 + 2 * ta;
    const int b = b0 + 2 * tb;
    const float bb = b2[0];
    const float qb0 = PQ[2 * B + b]     + PQ[3 * B + b]     + bb;
    const float qb1 = PQ[2 * B + b + 1] + PQ[3 * B + b + 1] + bb;
#pragma unroll
    for (int i = 0; i < 2; ++i) {
        const float pa = PQ[a + i] + PQ[B + a + i];
        float2 o;
        o.x = pa + qb0 + 0.5f * acc[i][0];
        o.y = pa + qb1 + 0.5f * acc[i][1];
        *(float2*)(out + (size_t)(a + i) * B + b) = o;
    }
}

extern "C" void kernel_launch(void* const* d_in, const int* in_sizes, int n_in,
                              void* d_out, int out_size, void* d_ws, size_t ws_size,
                              hipStream_t stream) {
    const float* x  = (const float*)d_in[0];
    const float* y  = (const float*)d_in[1];
    const float* W1 = (const float*)d_in[2];
    const float* b1 = (const float*)d_in[3];
    const float* W2 = (const float*)d_in[4];
    const float* b2 = (const float*)d_in[5];
    float* out = (float*)d_out;

    float* U  = (float*)d_ws;                 // B*H floats = 1 MB
    float* V  = U + (size_t)B * H;            // 1 MB
    float* PQ = V + (size_t)B * H;            // 4*B floats

    k1_uv<<<dim3(B / 4, 2, 2), 256, 0, stream>>>(x, y, W1, b1, W2, U, V, PQ);
    k2_pair<<<dim3(16, 16), 256, 0, stream>>>(U, V, W2, PQ, b2, out);
}